// Round 15
// baseline (126.703 us; speedup 1.0000x reference)
//
#include <hip/hip_runtime.h>
#include <hip/hip_bf16.h>
#include <stdint.h>

#define H_ 16
#define DH_ 64
#define B_ 8
#define S_ 1024
#define D_ 1024

using bf16 = __hip_bfloat16;
typedef __attribute__((ext_vector_type(8))) short bfrag;   // 8 x bf16 (16B) MFMA A/B frag
typedef __attribute__((ext_vector_type(4))) float facc;    // 4 x f32 MFMA C/D frag
typedef __attribute__((ext_vector_type(4))) float f4;

#define SWZ(r) ((((r) & 7) << 4) ^ (((r) & 8) << 3))   // 128B rows, 16B slots
#define SWZP(r) ((((r) >> 1) & 3) << 4)                 // 64B rows, 16B slots (0-conflict)

__device__ __forceinline__ int proj_len(int z, int Ql, int Vl) {
  if (z == 0) return Ql;                       // q: attn reads q-tiles with q0b < Ql
  if (z == 1) return Vl;                       // k: keys >= Vl never enter live scores
  return Vl ? Vl : min(Ql + 63, S_);           // v: Vl==0 -> uniform path reads causal v
}

// ---------------- W transpose f32->bf16, all 3 weights, (3072,1024) output ----------------
__global__ __launch_bounds__(256) void transpose_w3(const float* __restrict__ WQ,
                                                    const float* __restrict__ WK,
                                                    const float* __restrict__ WV,
                                                    bf16* __restrict__ WT) {
  __shared__ bf16 tile[32][33];
  int z = blockIdx.z;
  const float* W = (z == 0) ? WQ : (z == 1) ? WK : WV;
  float scale = (z == 0) ? 0.125f * 1.44269504f : 1.0f;   // fold 1/8 * log2(e) into WQ
  int tx = threadIdx.x & 31, ty = threadIdx.x >> 5;  // 32 x 8
  int bx = blockIdx.x, by = blockIdx.y;
#pragma unroll
  for (int i = 0; i < 4; ++i) {
    int kk = by * 32 + ty + 8 * i;
    int nn = bx * 32 + tx;
    tile[ty + 8 * i][tx] = __float2bfloat16(W[kk * D_ + nn] * scale);
  }
  __syncthreads();
#pragma unroll
  for (int i = 0; i < 4; ++i) {
    int nn = bx * 32 + ty + 8 * i;
    int kk = by * 32 + tx;
    WT[((size_t)z * 1024 + nn) * D_ + kk] = tile[tx][ty + 8 * i];
  }
}

// ---------------- Projection GEMM: fused f32-A (no convert pass), R13 decode ----------------
// A_z: (8192,1024) f32 directly from inputs; Bt: (3072,1024) bf16 stacked W^T.
// A staged to LDS as f32 via global_load_lds (SWZ-swizzled 128B rows), converted to bf16
// in-register after ds_read (RNE, numerically identical to the old convert+reload path).
// Grid decode (R13, measured best): fid in [0,1536): y=fid&7, z=(fid>>3)%3, x=fid/24.
// m-chunk x in HIGH bits -> co-resident blocks sweep x -> pruning idles a fraction of
// every CU instead of whole CUs.
__global__ __launch_bounds__(256) void proj_gemm(const float* __restrict__ A0,
                                                 const float* __restrict__ A1,
                                                 const float* __restrict__ A2,
                                                 const bf16* __restrict__ Bt,
                                                 bf16* __restrict__ qb,
                                                 bf16* __restrict__ kb,
                                                 bf16* __restrict__ vb,
                                                 const int* __restrict__ Qlen,
                                                 const int* __restrict__ Vlen) {
  __shared__ __align__(16) float Asf[128][32];   // 16 KB, 128B rows, SWZ-swizzled
  __shared__ __align__(16) bf16 Bs[128][32];     //  8 KB, 64B rows, SWZP-swizzled
  int fid = blockIdx.x;
  int y = fid & 7;
  int z = (fid >> 3) % 3;
  int x = fid / 24;           // 0..63
  int m0 = x * 128;
  int bb = m0 >> 10;
  int len = proj_len(z, Qlen[bb], Vlen[bb]);
  if ((m0 & (S_ - 1)) >= len) return;       // dead 128-row chunk: nobody reads it
  const float* A = (z == 0) ? A0 : (z == 1) ? A1 : A2;
  bf16* outp = (z == 0) ? qb : (z == 1) ? kb : vb;
  int tid = threadIdx.x;
  int lane = tid & 63;
  int wave = tid >> 6;
  int n0 = y * 128;
  int nw = z * 1024 + n0;                // row offset into stacked Bt
  int wm = (wave >> 1) * 64;
  int wn = (wave & 1) * 64;
  int l15 = lane & 15, l4 = lane >> 4;
  // B staging (bf16): lane covers row br of its 16-row group, slot lane&3, SWZP pre-swizzle
  int br = lane >> 2;
  int lc = ((lane & 3) ^ ((br >> 1) & 3)) * 8;
  // A staging (f32): per issue c, 8 rows x 8 slots; lane -> row lane>>3, slot lane&7
  int ar = lane >> 3;
  int as = (lane & 7) * 16;

  facc acc[4][4] = {};

  for (int k0 = 0; k0 < D_; k0 += 32) {
    __syncthreads();   // all waves done reading LDS from prev iter
    // ---- stage A (f32, 16 KB) : 4 issues/thread ----
#pragma unroll
    for (int c = 0; c < 4; ++c) {
      int rowb = wave * 32 + c * 8;      // wave-uniform 8-row group base
      int row = rowb + ar;
      const char* src = (const char*)&A[(size_t)(m0 + row) * D_ + k0] + (as ^ SWZ(row));
      char* dst = (char*)&Asf[0][0] + rowb * 128;
      __builtin_amdgcn_global_load_lds((const __attribute__((address_space(1))) void*)src,
                                       (__attribute__((address_space(3))) void*)dst, 16, 0, 0);
    }
    // ---- stage B (bf16, 8 KB) : 2 issues/thread ----
#pragma unroll
    for (int c = 0; c < 2; ++c) {
      int row = wave * 32 + c * 16;
      __builtin_amdgcn_global_load_lds(
          (const __attribute__((address_space(1))) void*)&Bt[(size_t)(nw + row + br) * D_ + k0 + lc],
          (__attribute__((address_space(3))) void*)&Bs[row][0], 16, 0, 0);
    }
    __syncthreads();   // barrier drains vmcnt -> tiles ready

    bfrag af[4], bfr[4];
    const char* Ab = (const char*)&Asf[0][0];
    const char* Bb = (const char*)&Bs[0][0];
#pragma unroll
    for (int i = 0; i < 4; ++i) {
      int row = wm + i * 16 + l15;
      const char* rp = Ab + row * 128;
      f4 lo = *(const f4*)(rp + ((l4 * 32) ^ SWZ(row)));
      f4 hi = *(const f4*)(rp + ((l4 * 32 + 16) ^ SWZ(row)));
      alignas(16) bf16 t[8];
#pragma unroll
      for (int j = 0; j < 4; ++j) {
        t[j] = __float2bfloat16(lo[j]);
        t[4 + j] = __float2bfloat16(hi[j]);
      }
      af[i] = *(const bfrag*)t;
    }
#pragma unroll
    for (int j = 0; j < 4; ++j) {
      int row = wn + j * 16 + l15;
      bfr[j] = *(const bfrag*)(Bb + row * 64 + ((l4 * 16) ^ SWZP(row)));
    }
#pragma unroll
    for (int i = 0; i < 4; ++i)
#pragma unroll
      for (int j = 0; j < 4; ++j)
        acc[i][j] = __builtin_amdgcn_mfma_f32_16x16x32_bf16(af[i], bfr[j], acc[i][j], 0, 0, 0);
  }

  // epilogue: C/D layout col = lane&15, row = (lane>>4)*4 + reg
  bool vmode = (z == 2);
#pragma unroll
  for (int i = 0; i < 4; ++i)
#pragma unroll
    for (int j = 0; j < 4; ++j)
#pragma unroll
      for (int r = 0; r < 4; ++r) {
        int gm = m0 + wm + i * 16 + l4 * 4 + r;
        int gn = n0 + wn + j * 16 + l15;
        int b = gm >> 10, sr = gm & (S_ - 1);
        int h = gn >> 6, dh = gn & 63;
        bf16 val = __float2bfloat16(acc[i][j][r]);
        if (!vmode)
          outp[(((size_t)b * H_ + h) * S_ + sr) * DH_ + dh] = val;
        else
          outp[(((size_t)b * H_ + h) * DH_ + dh) * S_ + sr] = val;
      }
}

// ---------------- Flash attention: dbuf LDS K/V, swapped-QK^T, LPT, length-pruned ----------------
// q,k: (B,H,S,DH) bf16 (q pre-scaled by log2e/8); vT: (B,H,DH,S) bf16; out: (B,S,H*DH) f32
__global__ __launch_bounds__(256) void attn_fwd(const bf16* __restrict__ q,
                                                const bf16* __restrict__ k,
                                                const bf16* __restrict__ vT,
                                                const int* __restrict__ Qlen,
                                                const int* __restrict__ Vlen,
                                                float* __restrict__ out) {
  __shared__ __align__(16) bf16 Kt[2][64 * 64];   // 8 KB each, row=key, XOR-swizzled
  __shared__ __align__(16) bf16 Vt[2][64 * 64];   // 8 KB each, row=d,   XOR-swizzled
  int tid = threadIdx.x, lane = tid & 63, wave = tid >> 6;
  int bid = blockIdx.x;
  int h = bid & 15, b = (bid >> 4) & 7;
  int qt = 15 - (bid >> 7);   // LPT: longest blocks dispatch FIRST; qt in [0,15]
  int q0b = qt * 64;
  int q0 = q0b + wave * 16;
  int Vl = Vlen[b], Ql = Qlen[b];
  int l15 = lane & 15, g = lane >> 4;
  int qrow = q0 + l15;

  if (q0b >= Ql) {   // whole 64-row q-tile masked: write zeros, exit
    f4 zz = {0.f, 0.f, 0.f, 0.f};
#pragma unroll
    for (int t = 0; t < 4; ++t)
      *(f4*)&out[((size_t)b * S_ + qrow) * (H_ * DH_) + h * DH_ + t * 16 + g * 4] = zz;
    return;
  }

  const bf16* qp = q + (size_t)(b * H_ + h) * S_ * DH_;
  const bf16* kp = k + (size_t)(b * H_ + h) * S_ * DH_;
  const bf16* vp = vT + (size_t)(b * H_ + h) * DH_ * S_;
  bool vzero = (Vl == 0);   // f32 ref: A-1e12 == -1e12 exactly -> exact uniform causal softmax

  int jlim = vzero ? (qrow + 1) : min(qrow + 1, Vl);
  int wmin = vzero ? (q0 + 1) : min(q0 + 1, Vl);
  int wmax = vzero ? (q0 + 16) : min(q0 + 16, Vl);
  if (q0 >= Ql) wmax = 0;   // fully-masked wave: keep barriers, skip compute

  bfrag qf0 = *(const bfrag*)&qp[(q0 + l15) * DH_ + g * 8];
  bfrag qf1 = *(const bfrag*)&qp[(q0 + l15) * DH_ + 32 + g * 8];

  facc o[4] = {};
  float mrow = -1e30f, lrow = 0.f;

  int kendb = q0b + 64;
  if (!vzero) kendb = kendb < Vl ? kendb : Vl;
  int nblk = (kendb + 63) >> 6;

  int krow0 = 8 * (l15 >> 2) + (l15 & 3);
  int sr0 = wave * 16 + (lane >> 3);
  int sbb = (lane & 7) * 16;

  auto stage = [&](int buf, int kbase) {
    int r0 = sr0, r1 = sr0 + 8;
    const char* kg0 = (const char*)(kp + (size_t)(kbase + r0) * DH_) + (sbb ^ SWZ(r0));
    const char* kg1 = (const char*)(kp + (size_t)(kbase + r1) * DH_) + (sbb ^ SWZ(r1));
    const char* vg0 = (const char*)(vp + (size_t)r0 * S_ + kbase) + (sbb ^ SWZ(r0));
    const char* vg1 = (const char*)(vp + (size_t)r1 * S_ + kbase) + (sbb ^ SWZ(r1));
    char* kl = (char*)&Kt[buf][0] + wave * 2048;
    char* vl = (char*)&Vt[buf][0] + wave * 2048;
    __builtin_amdgcn_global_load_lds((const __attribute__((address_space(1))) void*)kg0,
        (__attribute__((address_space(3))) void*)kl, 16, 0, 0);
    __builtin_amdgcn_global_load_lds((const __attribute__((address_space(1))) void*)kg1,
        (__attribute__((address_space(3))) void*)(kl + 1024), 16, 0, 0);
    __builtin_amdgcn_global_load_lds((const __attribute__((address_space(1))) void*)vg0,
        (__attribute__((address_space(3))) void*)vl, 16, 0, 0);
    __builtin_amdgcn_global_load_lds((const __attribute__((address_space(1))) void*)vg1,
        (__attribute__((address_space(3))) void*)(vl + 1024), 16, 0, 0);
  };

  stage(0, 0);
  __syncthreads();

  for (int kb = 0; kb < nblk; ++kb) {
    int cur = kb & 1;
    int kbase = kb * 64;
    if (kb + 1 < nblk) stage(1 - cur, (kb + 1) * 64);

    if (kbase < wmax) {
      facc z[4] = {};
      if (!vzero) {
#pragma unroll
        for (int gg = 0; gg < 2; ++gg) {
          int ra = gg * 32 + krow0;
          int rb = ra + 4;
          const char* Kc = (const char*)&Kt[cur][0];
          bfrag a0 = *(const bfrag*)(Kc + ra * 128 + ((g * 16) ^ SWZ(ra)));
          bfrag a1 = *(const bfrag*)(Kc + ra * 128 + ((g * 16 + 64) ^ SWZ(ra)));
          z[2 * gg] = __builtin_amdgcn_mfma_f32_16x16x32_bf16(a0, qf0, z[2 * gg], 0, 0, 0);
          z[2 * gg] = __builtin_amdgcn_mfma_f32_16x16x32_bf16(a1, qf1, z[2 * gg], 0, 0, 0);
          bfrag a2 = *(const bfrag*)(Kc + rb * 128 + ((g * 16) ^ SWZ(rb)));
          bfrag a3 = *(const bfrag*)(Kc + rb * 128 + ((g * 16 + 64) ^ SWZ(rb)));
          z[2 * gg + 1] = __builtin_amdgcn_mfma_f32_16x16x32_bf16(a2, qf0, z[2 * gg + 1], 0, 0, 0);
          z[2 * gg + 1] = __builtin_amdgcn_mfma_f32_16x16x32_bf16(a3, qf1, z[2 * gg + 1], 0, 0, 0);
        }
      }

      float sv[16];
#pragma unroll
      for (int gg = 0; gg < 2; ++gg)
#pragma unroll
        for (int c = 0; c < 4; ++c) {
          sv[8 * gg + c] = z[2 * gg][c];
          sv[8 * gg + 4 + c] = z[2 * gg + 1][c];
        }
      if (kbase + 64 > wmin) {
#pragma unroll
        for (int gg = 0; gg < 2; ++gg)
#pragma unroll
          for (int c = 0; c < 8; ++c) {
            int j = kbase + 32 * gg + 8 * g + c;
            if (j >= jlim) sv[8 * gg + c] = -1e12f;
          }
      }

      float mxl = sv[0];
#pragma unroll
      for (int c = 1; c < 16; ++c) mxl = fmaxf(mxl, sv[c]);

      if (!__all(mxl <= mrow + 8.0f)) {   // T13 defer-max (log2 domain)
        float mx = fmaxf(mxl, __shfl_xor(mxl, 16, 64));
        mx = fmaxf(mx, __shfl_xor(mx, 32, 64));
        float nm = fmaxf(mrow, mx);
        float sc = exp2f(mrow - nm);
        lrow *= sc;
#pragma unroll
        for (int t = 0; t < 4; ++t)
#pragma unroll
          for (int r = 0; r < 4; ++r) o[t][r] *= sc;
        mrow = nm;
      }

      alignas(16) bf16 pb[16];
      float ss = 0.f;
#pragma unroll
      for (int c = 0; c < 16; ++c) {
        float pv = exp2f(sv[c] - mrow);
        ss += pv;
        pb[c] = __float2bfloat16(pv);
      }
      ss += __shfl_xor(ss, 16, 64);
      ss += __shfl_xor(ss, 32, 64);
      lrow += ss;

      bfrag pf0 = *(const bfrag*)&pb[0];
      bfrag pf1 = *(const bfrag*)&pb[8];
      const char* Vc = (const char*)&Vt[cur][0];
#pragma unroll
      for (int t = 0; t < 4; ++t) {
        int d = t * 16 + l15;
        bfrag vf0 = *(const bfrag*)(Vc + d * 128 + ((g * 16) ^ SWZ(d)));
        bfrag vf1 = *(const bfrag*)(Vc + d * 128 + ((g * 16 + 64) ^ SWZ(d)));
        o[t] = __builtin_amdgcn_mfma_f32_16x16x32_bf16(vf0, pf0, o[t], 0, 0, 0);
        o[t] = __builtin_amdgcn_mfma_f32_16x16x32_bf16(vf1, pf1, o[t], 0, 0, 0);
      }
    }

    __syncthreads();
  }

  float inv = 1.0f / lrow;
  if (qrow >= Ql) inv = 0.f;
#pragma unroll
  for (int t = 0; t < 4; ++t) {
    f4 ov;
#pragma unroll
    for (int r = 0; r < 4; ++r) ov[r] = o[t][r] * inv;
    *(f4*)&out[((size_t)b * S_ + qrow) * (H_ * DH_) + h * DH_ + t * 16 + g * 4] = ov;
  }
}

extern "C" void kernel_launch(void* const* d_in, const int* in_sizes, int n_in,
                              void* d_out, int out_size, void* d_ws, size_t ws_size,
                              hipStream_t stream) {
  const float* Qs = (const float*)d_in[0];
  const float* Ks = (const float*)d_in[1];
  const float* Vs = (const float*)d_in[2];
  const int* Qlen = (const int*)d_in[3];
  const int* Vlen = (const int*)d_in[4];
  const float* WQ = (const float*)d_in[5];
  const float* WK = (const float*)d_in[6];
  const float* WV = (const float*)d_in[7];
  float* out = (float*)d_out;

  char* ws = (char*)d_ws;
  const size_t MB = 1024 * 1024;
  bf16* wT = (bf16*)(ws + 0 * MB);     // (3072,1024) stacked W^T, 6 MB
  bf16* qb = (bf16*)(ws + 6 * MB);     // (B,H,S,DH), 16 MB
  bf16* kb = (bf16*)(ws + 22 * MB);    // (B,H,S,DH), 16 MB
  bf16* vb = (bf16*)(ws + 38 * MB);    // (B,H,DH,S), 16 MB   -> 54 MB total
  dim3 tb(256);

  transpose_w3<<<dim3(32, 32, 3), tb, 0, stream>>>(WQ, WK, WV, wT);
  proj_gemm<<<dim3(1536, 1, 1), tb, 0, stream>>>(Qs, Ks, Vs, wT, qb, kb, vb, Qlen, Vlen);
  attn_fwd<<<dim3(B_ * H_ * (S_ / 64)), tb, 0, stream>>>(qb, kb, vb, Qlen, Vlen, out);
}

// Round 16
// 109.624 us; speedup vs baseline: 1.1558x; 1.1558x over previous
//
#include <hip/hip_runtime.h>
#include <hip/hip_bf16.h>
#include <stdint.h>

#define H_ 16
#define DH_ 64
#define B_ 8
#define S_ 1024
#define D_ 1024

using bf16 = __hip_bfloat16;
typedef __attribute__((ext_vector_type(8))) short bfrag;   // 8 x bf16 (16B) MFMA A/B frag
typedef __attribute__((ext_vector_type(4))) float facc;    // 4 x f32 MFMA C/D frag
typedef __attribute__((ext_vector_type(4))) float f4;

#define SWZ(r) ((((r) & 7) << 4) ^ (((r) & 8) << 3))   // attn: 128B rows
#define SWZP(r) ((((r) >> 1) & 3) << 4)                 // proj: 64B rows, 16B slots (0-conflict)

__device__ __forceinline__ int proj_len(int z, int Ql, int Vl) {
  if (z == 0) return Ql;                       // q: attn reads q-tiles with q0b < Ql
  if (z == 1) return Vl;                       // k: keys >= Vl never enter live scores
  return Vl ? Vl : min(Ql + 63, S_);           // v: Vl==0 -> uniform path reads causal v
}

// ---------------- f32 -> bf16 bulk convert (3 tensors, length-pruned) ----------------
__global__ __launch_bounds__(256) void convert3_f32_bf16(const float* __restrict__ Q,
                                                         const float* __restrict__ K,
                                                         const float* __restrict__ V,
                                                         bf16* __restrict__ o0,
                                                         bf16* __restrict__ o1,
                                                         bf16* __restrict__ o2,
                                                         const int* __restrict__ Qlen,
                                                         const int* __restrict__ Vlen) {
  int z = blockIdx.z;
  int row = blockIdx.x * 2;                 // block covers rows {row, row+1} of (8192, 1024)
  int bb = row >> 10;
  int lrow = row & (S_ - 1);
  int len = proj_len(z, Qlen[bb], Vlen[bb]);
  if ((lrow & ~127) >= len) return;         // same 128-chunk condition as proj_gemm
  const float* in = (z == 0) ? Q : (z == 1) ? K : V;
  bf16* outb = (z == 0) ? o0 : (z == 1) ? o1 : o2;
  int i = blockIdx.x * 256 + threadIdx.x;   // one thread = 8 elements
  f4 a = ((const f4*)in)[2 * i];
  f4 b = ((const f4*)in)[2 * i + 1];
  alignas(16) bf16 tmp[8];
#pragma unroll
  for (int j = 0; j < 4; ++j) tmp[j] = __float2bfloat16(a[j]);
#pragma unroll
  for (int j = 0; j < 4; ++j) tmp[4 + j] = __float2bfloat16(b[j]);
  *(bfrag*)&outb[8 * i] = *(const bfrag*)tmp;
}

// ---------------- W transpose f32->bf16, all 3 weights, (3072,1024) output ----------------
__global__ __launch_bounds__(256) void transpose_w3(const float* __restrict__ WQ,
                                                    const float* __restrict__ WK,
                                                    const float* __restrict__ WV,
                                                    bf16* __restrict__ WT) {
  __shared__ bf16 tile[32][33];
  int z = blockIdx.z;
  const float* W = (z == 0) ? WQ : (z == 1) ? WK : WV;
  float scale = (z == 0) ? 0.125f * 1.44269504f : 1.0f;   // fold 1/8 * log2(e) into WQ
  int tx = threadIdx.x & 31, ty = threadIdx.x >> 5;  // 32 x 8
  int bx = blockIdx.x, by = blockIdx.y;
#pragma unroll
  for (int i = 0; i < 4; ++i) {
    int kk = by * 32 + ty + 8 * i;
    int nn = bx * 32 + tx;
    tile[ty + 8 * i][tx] = __float2bfloat16(W[kk * D_ + nn] * scale);
  }
  __syncthreads();
#pragma unroll
  for (int i = 0; i < 4; ++i) {
    int nn = bx * 32 + ty + 8 * i;
    int kk = by * 32 + tx;
    WT[((size_t)z * 1024 + nn) * D_ + kk] = tile[tx][ty + 8 * i];
  }
}

// ---------------- Projection GEMM: R10 structure + anti-aliasing grid decode (R13) ----------------
// Flat grid. Batched (zbase<0): fid in [0,1536): y=fid&7, z=(fid>>3)%3, x=fid/24.
// m-chunk x lives in the HIGH bits of fid -> co-resident blocks (bid stride 256) sweep
// x by ~10.7/step, so pruning idles a FRACTION of every CU instead of 44% of all CUs.
// Serial (zbase>=0): fid in [0,512): y=fid&7, x=fid>>3.
__global__ __launch_bounds__(256) void proj_gemm(const bf16* __restrict__ A0,
                                                 const bf16* __restrict__ A1,
                                                 const bf16* __restrict__ A2,
                                                 const bf16* __restrict__ Bt,
                                                 bf16* __restrict__ qb,
                                                 bf16* __restrict__ kb,
                                                 bf16* __restrict__ vb,
                                                 const int* __restrict__ Qlen,
                                                 const int* __restrict__ Vlen,
                                                 int zbase) {
  __shared__ __align__(16) bf16 As[128][32];
  __shared__ __align__(16) bf16 Bs[128][32];
  int fid = blockIdx.x;
  int x, y, z;
  if (zbase < 0) {          // batched: 1536 blocks
    y = fid & 7;
    z = (fid >> 3) % 3;
    x = fid / 24;           // 0..63 (1536 = 64*24)
  } else {                  // serial: 512 blocks, fixed z
    y = fid & 7;
    x = fid >> 3;           // 0..63
    z = zbase;
  }
  int m0 = x * 128;
  int bb = m0 >> 10;
  int len = proj_len(z, Qlen[bb], Vlen[bb]);
  if ((m0 & (S_ - 1)) >= len) return;       // dead 128-row chunk: nobody reads it
  const bf16* A = (z == 0) ? A0 : (z == 1) ? A1 : A2;
  bf16* outp = (z == 0) ? qb : (z == 1) ? kb : vb;
  int tid = threadIdx.x;
  int lane = tid & 63;
  int wave = tid >> 6;
  int n0 = y * 128;
  int nw = z * 1024 + n0;                // row offset into stacked Bt
  int wm = (wave >> 1) * 64;
  int wn = (wave & 1) * 64;
  int l15 = lane & 15, l4 = lane >> 4;
  // staging: lane covers row br of its 16-row group, physical slot lane&3;
  // source column pre-swizzled so LDS content[row][p] = logical slot p ^ ((row>>1)&3)
  int br = lane >> 2;
  int lc = ((lane & 3) ^ ((br >> 1) & 3)) * 8;

  facc acc[4][4] = {};

  for (int k0 = 0; k0 < D_; k0 += 32) {
    __syncthreads();   // all waves done reading As/Bs from prev iter
#pragma unroll
    for (int c = 0; c < 2; ++c) {
      int row = wave * 32 + c * 16;      // wave-uniform group base
      __builtin_amdgcn_global_load_lds(
          (const __attribute__((address_space(1))) void*)&A[(size_t)(m0 + row + br) * D_ + k0 + lc],
          (__attribute__((address_space(3))) void*)&As[row][0], 16, 0, 0);
      __builtin_amdgcn_global_load_lds(
          (const __attribute__((address_space(1))) void*)&Bt[(size_t)(nw + row + br) * D_ + k0 + lc],
          (__attribute__((address_space(3))) void*)&Bs[row][0], 16, 0, 0);
    }
    __syncthreads();   // barrier drains vmcnt -> tiles ready
    bfrag af[4], bfr[4];
    const char* Ab = (const char*)&As[0][0];
    const char* Bb = (const char*)&Bs[0][0];
#pragma unroll
    for (int i = 0; i < 4; ++i) {
      int row = wm + i * 16 + l15;
      af[i] = *(const bfrag*)(Ab + row * 64 + ((l4 * 16) ^ SWZP(row)));
    }
#pragma unroll
    for (int j = 0; j < 4; ++j) {
      int row = wn + j * 16 + l15;
      bfr[j] = *(const bfrag*)(Bb + row * 64 + ((l4 * 16) ^ SWZP(row)));
    }
#pragma unroll
    for (int i = 0; i < 4; ++i)
#pragma unroll
      for (int j = 0; j < 4; ++j)
        acc[i][j] = __builtin_amdgcn_mfma_f32_16x16x32_bf16(af[i], bfr[j], acc[i][j], 0, 0, 0);
  }

  // epilogue: C/D layout col = lane&15, row = (lane>>4)*4 + reg
  bool vmode = (z == 2);
#pragma unroll
  for (int i = 0; i < 4; ++i)
#pragma unroll
    for (int j = 0; j < 4; ++j)
#pragma unroll
      for (int r = 0; r < 4; ++r) {
        int gm = m0 + wm + i * 16 + l4 * 4 + r;
        int gn = n0 + wn + j * 16 + l15;
        int b = gm >> 10, sr = gm & (S_ - 1);
        int h = gn >> 6, dh = gn & 63;
        bf16 val = __float2bfloat16(acc[i][j][r]);
        if (!vmode)
          outp[(((size_t)b * H_ + h) * S_ + sr) * DH_ + dh] = val;
        else
          outp[(((size_t)b * H_ + h) * DH_ + dh) * S_ + sr] = val;
      }
}

// ---------------- Flash attention: dbuf LDS K/V, swapped-QK^T, LPT, length-pruned ----------------
// q,k: (B,H,S,DH) bf16 (q pre-scaled by log2e/8); vT: (B,H,DH,S) bf16; out: (B,S,H*DH) f32
__global__ __launch_bounds__(256) void attn_fwd(const bf16* __restrict__ q,
                                                const bf16* __restrict__ k,
                                                const bf16* __restrict__ vT,
                                                const int* __restrict__ Qlen,
                                                const int* __restrict__ Vlen,
                                                float* __restrict__ out) {
  __shared__ __align__(16) bf16 Kt[2][64 * 64];   // 8 KB each, row=key, XOR-swizzled
  __shared__ __align__(16) bf16 Vt[2][64 * 64];   // 8 KB each, row=d,   XOR-swizzled
  int tid = threadIdx.x, lane = tid & 63, wave = tid >> 6;
  int bid = blockIdx.x;
  int h = bid & 15, b = (bid >> 4) & 7;
  int qt = 15 - (bid >> 7);   // LPT: longest blocks dispatch FIRST; qt in [0,15]
  int q0b = qt * 64;
  int q0 = q0b + wave * 16;
  int Vl = Vlen[b], Ql = Qlen[b];
  int l15 = lane & 15, g = lane >> 4;
  int qrow = q0 + l15;

  if (q0b >= Ql) {   // whole 64-row q-tile masked: write zeros, exit
    f4 zz = {0.f, 0.f, 0.f, 0.f};
#pragma unroll
    for (int t = 0; t < 4; ++t)
      *(f4*)&out[((size_t)b * S_ + qrow) * (H_ * DH_) + h * DH_ + t * 16 + g * 4] = zz;
    return;
  }

  const bf16* qp = q + (size_t)(b * H_ + h) * S_ * DH_;
  const bf16* kp = k + (size_t)(b * H_ + h) * S_ * DH_;
  const bf16* vp = vT + (size_t)(b * H_ + h) * DH_ * S_;
  bool vzero = (Vl == 0);   // f32 ref: A-1e12 == -1e12 exactly -> exact uniform causal softmax

  int jlim = vzero ? (qrow + 1) : min(qrow + 1, Vl);
  int wmin = vzero ? (q0 + 1) : min(q0 + 1, Vl);
  int wmax = vzero ? (q0 + 16) : min(q0 + 16, Vl);
  if (q0 >= Ql) wmax = 0;   // fully-masked wave: keep barriers, skip compute

  bfrag qf0 = *(const bfrag*)&qp[(q0 + l15) * DH_ + g * 8];
  bfrag qf1 = *(const bfrag*)&qp[(q0 + l15) * DH_ + 32 + g * 8];

  facc o[4] = {};
  float mrow = -1e30f, lrow = 0.f;

  int kendb = q0b + 64;
  if (!vzero) kendb = kendb < Vl ? kendb : Vl;
  int nblk = (kendb + 63) >> 6;

  int krow0 = 8 * (l15 >> 2) + (l15 & 3);
  int sr0 = wave * 16 + (lane >> 3);
  int sbb = (lane & 7) * 16;

  auto stage = [&](int buf, int kbase) {
    int r0 = sr0, r1 = sr0 + 8;
    const char* kg0 = (const char*)(kp + (size_t)(kbase + r0) * DH_) + (sbb ^ SWZ(r0));
    const char* kg1 = (const char*)(kp + (size_t)(kbase + r1) * DH_) + (sbb ^ SWZ(r1));
    const char* vg0 = (const char*)(vp + (size_t)r0 * S_ + kbase) + (sbb ^ SWZ(r0));
    const char* vg1 = (const char*)(vp + (size_t)r1 * S_ + kbase) + (sbb ^ SWZ(r1));
    char* kl = (char*)&Kt[buf][0] + wave * 2048;
    char* vl = (char*)&Vt[buf][0] + wave * 2048;
    __builtin_amdgcn_global_load_lds((const __attribute__((address_space(1))) void*)kg0,
        (__attribute__((address_space(3))) void*)kl, 16, 0, 0);
    __builtin_amdgcn_global_load_lds((const __attribute__((address_space(1))) void*)kg1,
        (__attribute__((address_space(3))) void*)(kl + 1024), 16, 0, 0);
    __builtin_amdgcn_global_load_lds((const __attribute__((address_space(1))) void*)vg0,
        (__attribute__((address_space(3))) void*)vl, 16, 0, 0);
    __builtin_amdgcn_global_load_lds((const __attribute__((address_space(1))) void*)vg1,
        (__attribute__((address_space(3))) void*)(vl + 1024), 16, 0, 0);
  };

  stage(0, 0);
  __syncthreads();

  for (int kb = 0; kb < nblk; ++kb) {
    int cur = kb & 1;
    int kbase = kb * 64;
    if (kb + 1 < nblk) stage(1 - cur, (kb + 1) * 64);

    if (kbase < wmax) {
      facc z[4] = {};
      if (!vzero) {
#pragma unroll
        for (int gg = 0; gg < 2; ++gg) {
          int ra = gg * 32 + krow0;
          int rb = ra + 4;
          const char* Kc = (const char*)&Kt[cur][0];
          bfrag a0 = *(const bfrag*)(Kc + ra * 128 + ((g * 16) ^ SWZ(ra)));
          bfrag a1 = *(const bfrag*)(Kc + ra * 128 + ((g * 16 + 64) ^ SWZ(ra)));
          z[2 * gg] = __builtin_amdgcn_mfma_f32_16x16x32_bf16(a0, qf0, z[2 * gg], 0, 0, 0);
          z[2 * gg] = __builtin_amdgcn_mfma_f32_16x16x32_bf16(a1, qf1, z[2 * gg], 0, 0, 0);
          bfrag a2 = *(const bfrag*)(Kc + rb * 128 + ((g * 16) ^ SWZ(rb)));
          bfrag a3 = *(const bfrag*)(Kc + rb * 128 + ((g * 16 + 64) ^ SWZ(rb)));
          z[2 * gg + 1] = __builtin_amdgcn_mfma_f32_16x16x32_bf16(a2, qf0, z[2 * gg + 1], 0, 0, 0);
          z[2 * gg + 1] = __builtin_amdgcn_mfma_f32_16x16x32_bf16(a3, qf1, z[2 * gg + 1], 0, 0, 0);
        }
      }

      float sv[16];
#pragma unroll
      for (int gg = 0; gg < 2; ++gg)
#pragma unroll
        for (int c = 0; c < 4; ++c) {
          sv[8 * gg + c] = z[2 * gg][c];
          sv[8 * gg + 4 + c] = z[2 * gg + 1][c];
        }
      if (kbase + 64 > wmin) {
#pragma unroll
        for (int gg = 0; gg < 2; ++gg)
#pragma unroll
          for (int c = 0; c < 8; ++c) {
            int j = kbase + 32 * gg + 8 * g + c;
            if (j >= jlim) sv[8 * gg + c] = -1e12f;
          }
      }

      float mxl = sv[0];
#pragma unroll
      for (int c = 1; c < 16; ++c) mxl = fmaxf(mxl, sv[c]);

      if (!__all(mxl <= mrow + 8.0f)) {   // T13 defer-max (log2 domain)
        float mx = fmaxf(mxl, __shfl_xor(mxl, 16, 64));
        mx = fmaxf(mx, __shfl_xor(mx, 32, 64));
        float nm = fmaxf(mrow, mx);
        float sc = exp2f(mrow - nm);
        lrow *= sc;
#pragma unroll
        for (int t = 0; t < 4; ++t)
#pragma unroll
          for (int r = 0; r < 4; ++r) o[t][r] *= sc;
        mrow = nm;
      }

      alignas(16) bf16 pb[16];
      float ss = 0.f;
#pragma unroll
      for (int c = 0; c < 16; ++c) {
        float pv = exp2f(sv[c] - mrow);
        ss += pv;
        pb[c] = __float2bfloat16(pv);
      }
      ss += __shfl_xor(ss, 16, 64);
      ss += __shfl_xor(ss, 32, 64);
      lrow += ss;

      bfrag pf0 = *(const bfrag*)&pb[0];
      bfrag pf1 = *(const bfrag*)&pb[8];
      const char* Vc = (const char*)&Vt[cur][0];
#pragma unroll
      for (int t = 0; t < 4; ++t) {
        int d = t * 16 + l15;
        bfrag vf0 = *(const bfrag*)(Vc + d * 128 + ((g * 16) ^ SWZ(d)));
        bfrag vf1 = *(const bfrag*)(Vc + d * 128 + ((g * 16 + 64) ^ SWZ(d)));
        o[t] = __builtin_amdgcn_mfma_f32_16x16x32_bf16(vf0, pf0, o[t], 0, 0, 0);
        o[t] = __builtin_amdgcn_mfma_f32_16x16x32_bf16(vf1, pf1, o[t], 0, 0, 0);
      }
    }

    __syncthreads();
  }

  float inv = 1.0f / lrow;
  if (qrow >= Ql) inv = 0.f;
#pragma unroll
  for (int t = 0; t < 4; ++t) {
    f4 ov;
#pragma unroll
    for (int r = 0; r < 4; ++r) ov[r] = o[t][r] * inv;
    *(f4*)&out[((size_t)b * S_ + qrow) * (H_ * DH_) + h * DH_ + t * 16 + g * 4] = ov;
  }
}

extern "C" void kernel_launch(void* const* d_in, const int* in_sizes, int n_in,
                              void* d_out, int out_size, void* d_ws, size_t ws_size,
                              hipStream_t stream) {
  const float* Qs = (const float*)d_in[0];
  const float* Ks = (const float*)d_in[1];
  const float* Vs = (const float*)d_in[2];
  const int* Qlen = (const int*)d_in[3];
  const int* Vlen = (const int*)d_in[4];
  const float* WQ = (const float*)d_in[5];
  const float* WK = (const float*)d_in[6];
  const float* WV = (const float*)d_in[7];
  float* out = (float*)d_out;

  char* ws = (char*)d_ws;
  const size_t MB = 1024 * 1024;
  bf16* wT = (bf16*)(ws + 0 * MB);     // (3072,1024) stacked W^T, 6 MB
  dim3 tb(256);
  const int CVT_GRID = (B_ * S_ * D_) / (8 * 256);   // 4096

  transpose_w3<<<dim3(32, 32, 3), tb, 0, stream>>>(WQ, WK, WV, wT);

  if (ws_size >= 102 * MB) {
    bf16* xc0 = (bf16*)(ws + 6 * MB);
    bf16* xc1 = (bf16*)(ws + 22 * MB);
    bf16* xc2 = (bf16*)(ws + 38 * MB);
    bf16* qb  = (bf16*)(ws + 54 * MB);
    bf16* kb  = (bf16*)(ws + 70 * MB);
    bf16* vb  = (bf16*)(ws + 86 * MB);
    convert3_f32_bf16<<<dim3(CVT_GRID, 1, 3), tb, 0, stream>>>(Qs, Ks, Vs, xc0, xc1, xc2,
                                                               Qlen, Vlen);
    proj_gemm<<<dim3(1536, 1, 1), tb, 0, stream>>>(xc0, xc1, xc2, wT, qb, kb, vb,
                                                   Qlen, Vlen, -1);
    attn_fwd<<<dim3(B_ * H_ * (S_ / 64)), tb, 0, stream>>>(qb, kb, vb, Qlen, Vlen, out);
  } else {
    bf16* xc = (bf16*)(ws + 6 * MB);
    bf16* qb = (bf16*)(ws + 22 * MB);
    bf16* kb = (bf16*)(ws + 38 * MB);
    bf16* vb = (bf16*)(ws + 54 * MB);
    convert3_f32_bf16<<<dim3(CVT_GRID, 1, 1), tb, 0, stream>>>(Qs, Ks, Vs, xc, xc, xc,
                                                               Qlen, Vlen);
    proj_gemm<<<dim3(512, 1, 1), tb, 0, stream>>>(xc, xc, xc, wT, qb, kb, vb, Qlen, Vlen, 0);
    convert3_f32_bf16<<<dim3(CVT_GRID, 1, 1), tb, 0, stream>>>(Ks, Ks, Ks, xc, xc, xc,
                                                               Qlen, Vlen);
    proj_gemm<<<dim3(512, 1, 1), tb, 0, stream>>>(xc, xc, xc, wT, qb, kb, vb, Qlen, Vlen, 1);
    convert3_f32_bf16<<<dim3(CVT_GRID, 1, 1), tb, 0, stream>>>(Vs, Vs, Vs, xc, xc, xc,
                                                               Qlen, Vlen);
    proj_gemm<<<dim3(512, 1, 1), tb, 0, stream>>>(xc, xc, xc, wT, qb, kb, vb, Qlen, Vlen, 2);
    attn_fwd<<<dim3(B_ * H_ * (S_ / 64)), tb, 0, stream>>>(qb, kb, vb, Qlen, Vlen, out);
  }
}